// Round 1
// baseline (707.904 us; speedup 1.0000x reference)
//
#include <hip/hip_runtime.h>
#include <math.h>

// Problem constants (from reference): B=16, DIM=512, SIZE=128
#define BB   16
#define CC   512
#define SS   128
#define HWSZ (SS * SS)   // 16384
#define NCH  16          // channel chunks for k1a
#define CK   (CC / NCH)  // 32 channels per chunk

// -----------------------------------------------------------------------------
// Kernel 1a: partial channel reduction with FULLY CONTIGUOUS streaming.
//
// grid = 16 b x 16 channel-chunks = 256 blocks (exactly 1/CU), 1024 threads
// (16 waves/CU). Each block owns 32 whole channel planes of one batch element:
// a single contiguous 2-MB region of x. Threads sweep each 64-KB plane in 4
// passes of 1024 float4 loads -> every wave issues full-width 1-KB coalesced
// requests in strictly ascending address order (same pattern as the 6.4 TB/s
// harness fill, read-side). 32 accumulators/thread in registers; partials
// written to workspace (part[b][ck][o][pix], 32 MB total).
// -----------------------------------------------------------------------------
__global__ __launch_bounds__(1024) void k1a_partial(
    const float* __restrict__ x, const float* __restrict__ wconv,
    float* __restrict__ part)
{
    const int b   = blockIdx.x >> 4;          // 16 chunks per batch
    const int ck  = blockIdx.x & (NCH - 1);   // channel chunk
    const int tid = threadIdx.x;

    const float* xp = x + ((size_t)b * CC + (size_t)ck * CK) * HWSZ + tid * 4;
    const float* wA = wconv + ck * CK;        // o = 0 weights (uniform -> SGPR)
    const float* wB = wconv + CC + ck * CK;   // o = 1 weights

    float4 a0[4], a1[4];
    #pragma unroll
    for (int s = 0; s < 4; ++s) {
        a0[s] = make_float4(0.f, 0.f, 0.f, 0.f);
        a1[s] = make_float4(0.f, 0.f, 0.f, 0.f);
    }

    #pragma unroll 2
    for (int c = 0; c < CK; ++c) {
        const float wa = wA[c];
        const float wb = wB[c];
        #pragma unroll
        for (int s = 0; s < 4; ++s) {
            const float4 v = *(const float4*)(xp + (size_t)c * HWSZ + s * 4096);
            a0[s].x = fmaf(v.x, wa, a0[s].x);
            a0[s].y = fmaf(v.y, wa, a0[s].y);
            a0[s].z = fmaf(v.z, wa, a0[s].z);
            a0[s].w = fmaf(v.w, wa, a0[s].w);
            a1[s].x = fmaf(v.x, wb, a1[s].x);
            a1[s].y = fmaf(v.y, wb, a1[s].y);
            a1[s].z = fmaf(v.z, wb, a1[s].z);
            a1[s].w = fmaf(v.w, wb, a1[s].w);
        }
    }

    float* pp = part + (size_t)(b * NCH + ck) * 2 * HWSZ + tid * 4;
    #pragma unroll
    for (int s = 0; s < 4; ++s) {
        *(float4*)(pp + s * 4096)        = a0[s];   // o = 0
        *(float4*)(pp + HWSZ + s * 4096) = a1[s];   // o = 1
    }
}

// -----------------------------------------------------------------------------
// Kernel 1b: reduce the 16 chunk-partials per pixel; emit x2 and transposed
// x2t. grid = 16 b x 2 o x 16 pixel-chunks = 512 blocks, 256 threads; each
// thread owns one float4 output and sums 16 fully-independent strided loads
// (all in flight at once). 64 MB read + 4 MB write total -> ~15 us.
// -----------------------------------------------------------------------------
__global__ __launch_bounds__(256) void k1b_reduce(
    const float* __restrict__ part, float* __restrict__ x2,
    float* __restrict__ x2t)
{
    const int pc  = blockIdx.x & 15;          // pixel chunk (256 quads)
    const int o   = (blockIdx.x >> 4) & 1;
    const int b   = blockIdx.x >> 5;
    const int tid = threadIdx.x;

    const int p = (pc * 256 + tid) * 4;       // flat pixel of this quad

    const float* pp = part + ((size_t)(b * NCH) * 2 + o) * HWSZ + p;
    float4 s = make_float4(0.f, 0.f, 0.f, 0.f);
    #pragma unroll
    for (int ck = 0; ck < NCH; ++ck) {
        const float4 v = *(const float4*)(pp + (size_t)ck * 2 * HWSZ);
        s.x += v.x; s.y += v.y; s.z += v.z; s.w += v.w;
    }

    *(float4*)&x2[(size_t)(b * 2 + o) * HWSZ + p] = s;

    // transposed layout [b,o,w,h]: scattered dwords, 2 MB total -> L2 absorbs
    const int h  = p >> 7;
    const int w0 = p & 127;
    float* t = x2t + ((size_t)(b * 2 + o) * SS + w0) * SS + h;
    t[0 * SS] = s.x;
    t[1 * SS] = s.y;
    t[2 * SS] = s.z;
    t[3 * SS] = s.w;
}

// -----------------------------------------------------------------------------
// Kernel 2: everything else, one block per batch element b (16 blocks).
// Now 512 threads: quadrants q=0,1 run the ww-conv partials while q=2,3 run
// the hw-conv partials CONCURRENTLY (they were sequential before -> halves
// the latency-bound reduction time). Then shifted combine, linear+sigmoid,
// outer-product store.
// -----------------------------------------------------------------------------
__global__ __launch_bounds__(512) void k2_rest(
    const float* __restrict__ x2, const float* __restrict__ x2t,
    const float* __restrict__ wwc,   // [2,128,5]
    const float* __restrict__ hwc,   // [2,5,128]
    const float* __restrict__ wlw, const float* __restrict__ wlb,
    const float* __restrict__ hlw, const float* __restrict__ hlb,
    float* __restrict__ out)
{
    __shared__ float tw[2][5][SS];   // ww partials, per input channel half
    __shared__ float uh[2][5][SS];   // hw partials
    __shared__ float vbuf[2 * SS];   // conv outputs: [0..127]=ww, [128..255]=hw
    __shared__ float rbuf[2 * SS];   // post-sigmoid: [0..127]=ww2, [128..255]=hw2

    const int b        = blockIdx.x;
    const int tid      = threadIdx.x;
    const int lane_pos = tid & 127;
    const int q        = tid >> 7;    // 0..3, wave-uniform
    const int half     = q & 1;       // input channel i of x2
    const int half_u   = __builtin_amdgcn_readfirstlane(half);

    if (q < 2) {
        // tw[half][kw][wo] = sum_kh x2[b,half,kh,wo] * wwc[half,kh,kw]
        const float* xrow = x2 + (size_t)(b * 2 + half) * HWSZ + lane_pos;
        const float* wrow = wwc + half_u * (SS * 5);
        float acc[5] = {0.f, 0.f, 0.f, 0.f, 0.f};
        #pragma unroll 8
        for (int kh = 0; kh < SS; ++kh) {
            const float xv = xrow[(size_t)kh * SS];   // coalesced across lanes
            #pragma unroll
            for (int kw = 0; kw < 5; ++kw)
                acc[kw] = fmaf(xv, wrow[kh * 5 + kw], acc[kw]);
        }
        #pragma unroll
        for (int kw = 0; kw < 5; ++kw) tw[half][kw][lane_pos] = acc[kw];
    } else {
        // uh[half][kh][ho] = sum_kw x2t[b,half,kw,ho] * hwc[half,kh,kw]
        const float* xcol = x2t + (size_t)(b * 2 + half) * HWSZ + lane_pos;
        const float* wrow = hwc + half_u * (5 * SS);
        float acc[5] = {0.f, 0.f, 0.f, 0.f, 0.f};
        #pragma unroll 8
        for (int kw = 0; kw < SS; ++kw) {
            const float xv = xcol[(size_t)kw * SS];   // coalesced (transposed)
            #pragma unroll
            for (int kh = 0; kh < 5; ++kh)
                acc[kh] = fmaf(xv, wrow[kh * SS + kw], acc[kh]);
        }
        #pragma unroll
        for (int kh = 0; kh < 5; ++kh) uh[half][kh][lane_pos] = acc[kh];
    }
    __syncthreads();

    // phase 3: shifted combine -> conv outputs (first 256 threads)
    if (tid < 256) {
        float s = 0.f;
        if (half == 0) {
            const int wo = lane_pos;
            #pragma unroll
            for (int kw = 0; kw < 5; ++kw) {
                const int wsrc = wo + kw - 2;
                if (wsrc >= 0 && wsrc < SS) s += tw[0][kw][wsrc] + tw[1][kw][wsrc];
            }
        } else {
            const int ho = lane_pos;
            #pragma unroll
            for (int kh = 0; kh < 5; ++kh) {
                const int hsrc = ho + kh - 2;
                if (hsrc >= 0 && hsrc < SS) s += uh[0][kh][hsrc] + uh[1][kh][hsrc];
            }
        }
        vbuf[tid] = s;
    }
    __syncthreads();

    // phase 4: linear (out[j] = sum_k v[k] * W[j,k] + b[j]) + sigmoid
    if (tid < 256) {
        const int j = lane_pos;
        const float* lw  = (half == 0) ? wlw : hlw;
        const float* lb  = (half == 0) ? wlb : hlb;
        const float* vin = vbuf + half * SS;   // LDS broadcast reads
        float s = lb[j];
        const float4* wr = (const float4*)(lw + (size_t)j * SS);
        #pragma unroll 4
        for (int k4 = 0; k4 < SS / 4; ++k4) {
            const float4 wv = wr[k4];
            s = fmaf(vin[4 * k4 + 0], wv.x, s);
            s = fmaf(vin[4 * k4 + 1], wv.y, s);
            s = fmaf(vin[4 * k4 + 2], wv.z, s);
            s = fmaf(vin[4 * k4 + 3], wv.w, s);
        }
        rbuf[tid] = 1.f / (1.f + expf(-s));
    }
    __syncthreads();

    // phase 5: out[b,h,w] = hw2[h] * ww2[w]  (float4 coalesced stores)
    {
        float* ob = out + (size_t)b * HWSZ;
        for (int p4 = tid; p4 < HWSZ / 4; p4 += 512) {
            const int h  = p4 >> 5;
            const int w0 = (p4 & 31) * 4;
            const float hv = rbuf[SS + h];
            float4 o;
            o.x = hv * rbuf[w0 + 0];
            o.y = hv * rbuf[w0 + 1];
            o.z = hv * rbuf[w0 + 2];
            o.w = hv * rbuf[w0 + 3];
            *(float4*)(ob + (size_t)h * SS + w0) = o;
        }
    }
}

extern "C" void kernel_launch(void* const* d_in, const int* in_sizes, int n_in,
                              void* d_out, int out_size, void* d_ws, size_t ws_size,
                              hipStream_t stream) {
    const float* x     = (const float*)d_in[0];  // [16,512,128,128]
    const float* wconv = (const float*)d_in[1];  // [2,512,1,1]
    const float* wwc   = (const float*)d_in[2];  // [1,2,128,5]
    const float* hwc   = (const float*)d_in[3];  // [1,2,5,128]
    const float* wlw   = (const float*)d_in[4];  // [128,128]
    const float* wlb   = (const float*)d_in[5];  // [128]
    const float* hlw   = (const float*)d_in[6];  // [128,128]
    const float* hlb   = (const float*)d_in[7];  // [128]
    float* out = (float*)d_out;                  // [16,128,128] fp32

    // workspace: x2 (2 MB) + x2t (2 MB) + part (32 MB)
    float* x2   = (float*)d_ws;
    float* x2t  = x2 + (size_t)BB * 2 * HWSZ;
    float* part = x2t + (size_t)BB * 2 * HWSZ;

    k1a_partial<<<dim3(BB * NCH), dim3(1024), 0, stream>>>(x, wconv, part);
    k1b_reduce<<<dim3(BB * 2 * 16), dim3(256), 0, stream>>>(part, x2, x2t);
    k2_rest<<<dim3(BB), dim3(512), 0, stream>>>(x2, x2t, wwc, hwc,
                                                wlw, wlb, hlw, hlb, out);
}

// Round 2
// 688.960 us; speedup vs baseline: 1.0275x; 1.0275x over previous
//
#include <hip/hip_runtime.h>
#include <math.h>

// Problem constants (from reference): B=16, DIM=512, SIZE=128
#define BB   16
#define CC   512
#define SS   128
#define HWSZ (SS * SS)   // 16384
#define NCH  16          // channel chunks for k1a
#define CK   (CC / NCH)  // 32 channels per chunk
#define LP   (SS + 1)    // padded LDS row stride (bank-conflict-free rows AND cols)

typedef float f4 __attribute__((ext_vector_type(4)));

// -----------------------------------------------------------------------------
// Kernel 1a: partial channel reduction, fully contiguous streaming + NON-
// TEMPORAL loads. grid = 16 b x 16 channel-chunks = 256 blocks (1/CU), 1024
// threads (16 waves/CU). Each block owns a contiguous 2-MB region of x (32
// channel planes of one b). x has ZERO reuse -> nt loads skip cache
// allocation (no LLC/L2 eviction churn against the poisoned workspace).
// Partials (32 MB) stored with REGULAR stores so they stay LLC-resident for
// k2's reduction read.
// -----------------------------------------------------------------------------
__global__ __launch_bounds__(1024) void k1a_partial(
    const float* __restrict__ x, const float* __restrict__ wconv,
    float* __restrict__ part)
{
    const int b   = blockIdx.x >> 4;          // 16 chunks per batch
    const int ck  = blockIdx.x & (NCH - 1);   // channel chunk
    const int tid = threadIdx.x;

    const float* xp = x + ((size_t)b * CC + (size_t)ck * CK) * HWSZ + tid * 4;
    const float* wA = wconv + ck * CK;        // o = 0 weights (uniform -> s_load)
    const float* wB = wconv + CC + ck * CK;   // o = 1 weights

    f4 a0[4], a1[4];
    #pragma unroll
    for (int s = 0; s < 4; ++s) { a0[s] = (f4)0.f; a1[s] = (f4)0.f; }

    #pragma unroll 4
    for (int c = 0; c < CK; ++c) {
        const float wa = wA[c];
        const float wb = wB[c];
        #pragma unroll
        for (int s = 0; s < 4; ++s) {
            const f4 v = __builtin_nontemporal_load(
                (const f4*)(xp + (size_t)c * HWSZ + s * 4096));
            a0[s].x = fmaf(v.x, wa, a0[s].x);
            a0[s].y = fmaf(v.y, wa, a0[s].y);
            a0[s].z = fmaf(v.z, wa, a0[s].z);
            a0[s].w = fmaf(v.w, wa, a0[s].w);
            a1[s].x = fmaf(v.x, wb, a1[s].x);
            a1[s].y = fmaf(v.y, wb, a1[s].y);
            a1[s].z = fmaf(v.z, wb, a1[s].z);
            a1[s].w = fmaf(v.w, wb, a1[s].w);
        }
    }

    float* pp = part + (size_t)(b * NCH + ck) * 2 * HWSZ + tid * 4;
    #pragma unroll
    for (int s = 0; s < 4; ++s) {
        *(f4*)(pp + s * 4096)        = a0[s];   // o = 0
        *(f4*)(pp + HWSZ + s * 4096) = a1[s];   // o = 1
    }
}

// -----------------------------------------------------------------------------
// Kernel 2: fused {16-partial reduce -> LDS x2 image -> both conv branches ->
// linear+sigmoid -> outer product}. One block per batch element (16 blocks,
// 1024 threads). The +1-padded LDS x2 image serves BOTH row reads (hw branch)
// and column reads (ww branch) conflict-free, eliminating the transposed
// global buffer and the separate k1b kernel entirely.
// LDS: 2*128*129*4 = 129 KB + 20 KB partials + 2 KB = ~151 KB (fits 160 KB/CU).
// -----------------------------------------------------------------------------
__global__ __launch_bounds__(1024) void k2_rest(
    const float* __restrict__ part,
    const float* __restrict__ wwc,   // [2,128,5]
    const float* __restrict__ hwc,   // [2,5,128]
    const float* __restrict__ wlw, const float* __restrict__ wlb,
    const float* __restrict__ hlw, const float* __restrict__ hlb,
    float* __restrict__ out)
{
    __shared__ float x2l[2][SS][LP];      // reduced x2 image, padded rows
    __shared__ float tw2[2][2][5][SS];    // [kpart][i][kw][wo] ww partials
    __shared__ float uh2[2][2][5][SS];    // [kpart][i][kh][ho] hw partials
    __shared__ float vbuf[2 * SS];        // conv outputs: [0..127]=ww, [128..]=hw
    __shared__ float rbuf[2 * SS];        // post-sigmoid

    const int b   = blockIdx.x;
    const int tid = threadIdx.x;

    // ---- phase 0: reduce 16 chunk-partials -> x2l (summation order == old k1b)
    {
        const float* pb = part + (size_t)b * NCH * 2 * HWSZ;
        #pragma unroll
        for (int it = 0; it < (2 * HWSZ / 4) / 1024; ++it) {   // 8 iters
            const int q4 = it * 1024 + tid;
            const int p  = q4 * 4;                  // flat [o][pix]
            const float* pp = pb + p;
            f4 s = (f4)0.f;
            #pragma unroll
            for (int c = 0; c < NCH; ++c) {
                const f4 v = *(const f4*)(pp + (size_t)c * 2 * HWSZ);
                s.x += v.x; s.y += v.y; s.z += v.z; s.w += v.w;
            }
            const int o   = p >> 14;                // / HWSZ
            const int pix = p & (HWSZ - 1);
            const int h   = pix >> 7;
            const int w   = pix & (SS - 1);
            x2l[o][h][w + 0] = s.x;
            x2l[o][h][w + 1] = s.y;
            x2l[o][h][w + 2] = s.z;
            x2l[o][h][w + 3] = s.w;
        }
    }
    __syncthreads();

    // ---- phase 1: both conv branches, 8 groups of 128 threads:
    // tid = [kp:1][br:1][i:1][lane:7] ; kp halves the 128-long reduction.
    {
        const int lane = tid & 127;
        const int i    = (tid >> 7) & 1;   // input channel (wave-uniform)
        const int br   = (tid >> 8) & 1;   // 0 = ww branch, 1 = hw branch
        const int kp   = tid >> 9;         // reduction half
        float acc[5] = {0.f, 0.f, 0.f, 0.f, 0.f};

        if (br == 0) {
            // tw2[kp][i][kw][wo] = sum_{kh in half} x2l[i][kh][wo] * wwc[i,kh,kw]
            const float* wrow = wwc + i * (SS * 5);
            const int kh0 = kp * 64;
            #pragma unroll 8
            for (int kh = kh0; kh < kh0 + 64; ++kh) {
                const float xv = x2l[i][kh][lane];         // col read: conflict-free (LP=129)
                #pragma unroll
                for (int kw = 0; kw < 5; ++kw)
                    acc[kw] = fmaf(xv, wrow[kh * 5 + kw], acc[kw]);
            }
            #pragma unroll
            for (int kw = 0; kw < 5; ++kw) tw2[kp][i][kw][lane] = acc[kw];
        } else {
            // uh2[kp][i][kh][ho] = sum_{kw in half} x2l[i][ho][kw] * hwc[i,kh,kw]
            const float* wrow = hwc + i * (5 * SS);
            const int kw0 = kp * 64;
            #pragma unroll 8
            for (int kw = kw0; kw < kw0 + 64; ++kw) {
                const float xv = x2l[i][lane][kw];         // row read: 2-way max (free)
                #pragma unroll
                for (int kh = 0; kh < 5; ++kh)
                    acc[kh] = fmaf(xv, wrow[kh * SS + kw], acc[kh]);
            }
            #pragma unroll
            for (int kh = 0; kh < 5; ++kh) uh2[kp][i][kh][lane] = acc[kh];
        }
    }
    __syncthreads();

    // ---- phase 2: shifted 5-tap combine over {kp, i}
    if (tid < 256) {
        const int pos = tid & 127;
        float s = 0.f;
        if (tid < 128) {                       // ww branch, wo = pos
            #pragma unroll
            for (int kw = 0; kw < 5; ++kw) {
                const int wsrc = pos + kw - 2;
                if (wsrc >= 0 && wsrc < SS)
                    s += (tw2[0][0][kw][wsrc] + tw2[0][1][kw][wsrc])
                       + (tw2[1][0][kw][wsrc] + tw2[1][1][kw][wsrc]);
            }
        } else {                               // hw branch, ho = pos
            #pragma unroll
            for (int kh = 0; kh < 5; ++kh) {
                const int hsrc = pos + kh - 2;
                if (hsrc >= 0 && hsrc < SS)
                    s += (uh2[0][0][kh][hsrc] + uh2[0][1][kh][hsrc])
                       + (uh2[1][0][kh][hsrc] + uh2[1][1][kh][hsrc]);
            }
        }
        vbuf[tid] = s;
    }
    __syncthreads();

    // ---- phase 3: linear + sigmoid
    if (tid < 256) {
        const int j    = tid & 127;
        const int half = tid >> 7;             // 0 = ww, 1 = hw
        const float* lw  = (half == 0) ? wlw : hlw;
        const float* lb  = (half == 0) ? wlb : hlb;
        const float* vin = vbuf + half * SS;
        float s = lb[j];
        const f4* wr = (const f4*)(lw + (size_t)j * SS);
        #pragma unroll 4
        for (int k4 = 0; k4 < SS / 4; ++k4) {
            const f4 wv = wr[k4];
            s = fmaf(vin[4 * k4 + 0], wv.x, s);
            s = fmaf(vin[4 * k4 + 1], wv.y, s);
            s = fmaf(vin[4 * k4 + 2], wv.z, s);
            s = fmaf(vin[4 * k4 + 3], wv.w, s);
        }
        rbuf[tid] = 1.f / (1.f + expf(-s));
    }
    __syncthreads();

    // ---- phase 4: out[b,h,w] = hw2[h] * ww2[w]
    {
        float* ob = out + (size_t)b * HWSZ;
        #pragma unroll
        for (int it = 0; it < (HWSZ / 4) / 1024; ++it) {   // 4 iters
            const int p4 = it * 1024 + tid;
            const int h  = p4 >> 5;
            const int w0 = (p4 & 31) * 4;
            const float hv = rbuf[SS + h];
            f4 o;
            o.x = hv * rbuf[w0 + 0];
            o.y = hv * rbuf[w0 + 1];
            o.z = hv * rbuf[w0 + 2];
            o.w = hv * rbuf[w0 + 3];
            *(f4*)(ob + (size_t)h * SS + w0) = o;
        }
    }
}

extern "C" void kernel_launch(void* const* d_in, const int* in_sizes, int n_in,
                              void* d_out, int out_size, void* d_ws, size_t ws_size,
                              hipStream_t stream) {
    const float* x     = (const float*)d_in[0];  // [16,512,128,128]
    const float* wconv = (const float*)d_in[1];  // [2,512,1,1]
    const float* wwc   = (const float*)d_in[2];  // [1,2,128,5]
    const float* hwc   = (const float*)d_in[3];  // [1,2,5,128]
    const float* wlw   = (const float*)d_in[4];  // [128,128]
    const float* wlb   = (const float*)d_in[5];  // [128]
    const float* hlw   = (const float*)d_in[6];  // [128,128]
    const float* hlb   = (const float*)d_in[7];  // [128]
    float* out = (float*)d_out;                  // [16,128,128] fp32

    // workspace: part (32 MB) only — x2/x2t round-trip eliminated
    float* part = (float*)d_ws;

    k1a_partial<<<dim3(BB * NCH), dim3(1024), 0, stream>>>(x, wconv, part);
    k2_rest<<<dim3(BB), dim3(1024), 0, stream>>>(part, wwc, hwc,
                                                 wlw, wlb, hlw, hlb, out);
}

// Round 3
// 681.489 us; speedup vs baseline: 1.0388x; 1.0110x over previous
//
#include <hip/hip_runtime.h>
#include <math.h>

// Problem constants (from reference): B=16, DIM=512, SIZE=128
#define BB   16
#define CC   512
#define SS   128
#define HWSZ (SS * SS)   // 16384
#define NCH  16          // channel chunks
#define CK   (CC / NCH)  // 32 channels per chunk
#define LP   (SS + 1)    // padded LDS row stride (conflict-free rows AND cols)

typedef float f4 __attribute__((ext_vector_type(4)));

// -----------------------------------------------------------------------------
// Kernel 1a: partial channel reduction, contiguous streaming, 2 blocks/CU.
// grid = 16 b x 16 ck x 2 half-planes = 512 blocks, 512 threads (8 waves).
// Each block streams a 1-MB region (32 channel planes x 32-KB half-plane,
// 32-KB contiguous pieces). Two independent blocks per CU give two separate
// issue streams. Partials part[b][ck][o][pix] (32 MB) with regular stores
// (re-read by k1b moments later -> keep LLC-resident).
// -----------------------------------------------------------------------------
__global__ __launch_bounds__(512) void k1a_partial(
    const float* __restrict__ x, const float* __restrict__ wconv,
    float* __restrict__ part)
{
    const int b   = blockIdx.x >> 5;
    const int sub = blockIdx.x & 31;
    const int ck  = sub >> 1;         // channel chunk
    const int hh  = sub & 1;          // half of the 16K-pixel plane
    const int tid = threadIdx.x;

    const float* xp = x + ((size_t)b * CC + (size_t)ck * CK) * HWSZ
                        + hh * (HWSZ / 2) + tid * 4;
    const float* wA = wconv + ck * CK;        // o = 0 weights (uniform)
    const float* wB = wconv + CC + ck * CK;   // o = 1 weights

    f4 a0[4], a1[4];
    #pragma unroll
    for (int s = 0; s < 4; ++s) { a0[s] = (f4)0.f; a1[s] = (f4)0.f; }

    #pragma unroll 4
    for (int c = 0; c < CK; ++c) {
        const float wa = wA[c];
        const float wb = wB[c];
        #pragma unroll
        for (int s = 0; s < 4; ++s) {   // 512 thr x 4 floats = 2048-float passes
            const f4 v = __builtin_nontemporal_load(
                (const f4*)(xp + (size_t)c * HWSZ + s * 2048));
            a0[s].x = fmaf(v.x, wa, a0[s].x);
            a0[s].y = fmaf(v.y, wa, a0[s].y);
            a0[s].z = fmaf(v.z, wa, a0[s].z);
            a0[s].w = fmaf(v.w, wa, a0[s].w);
            a1[s].x = fmaf(v.x, wb, a1[s].x);
            a1[s].y = fmaf(v.y, wb, a1[s].y);
            a1[s].z = fmaf(v.z, wb, a1[s].z);
            a1[s].w = fmaf(v.w, wb, a1[s].w);
        }
    }

    float* pp = part + (size_t)(b * NCH + ck) * 2 * HWSZ
                     + hh * (HWSZ / 2) + tid * 4;
    #pragma unroll
    for (int s = 0; s < 4; ++s) {
        *(f4*)(pp + s * 2048)        = a0[s];   // o = 0
        *(f4*)(pp + HWSZ + s * 2048) = a1[s];   // o = 1
    }
}

// -----------------------------------------------------------------------------
// Kernel 1b: WIDE partial reduce (fixes round-2's 16-CU/32-MB phase-0
// bottleneck). grid = 16 b x 2 o x 16 pixel-chunks = 512 blocks, 256 thr.
// Each thread owns one float4 and sums 16 independent strided loads (all in
// flight). 32 MB read + 4 MB write on 512 blocks -> ~8-10 us. Summation order
// (ck = 0..15 sequential) identical to previous rounds -> bit-identical out.
// -----------------------------------------------------------------------------
__global__ __launch_bounds__(256) void k1b_reduce(
    const float* __restrict__ part, float* __restrict__ x2)
{
    const int pc  = blockIdx.x & 15;
    const int o   = (blockIdx.x >> 4) & 1;
    const int b   = blockIdx.x >> 5;
    const int tid = threadIdx.x;

    const int p = (pc * 256 + tid) * 4;

    const float* pp = part + ((size_t)(b * NCH) * 2 + o) * HWSZ + p;
    f4 s = (f4)0.f;
    #pragma unroll
    for (int ck = 0; ck < NCH; ++ck) {
        const f4 v = *(const f4*)(pp + (size_t)ck * 2 * HWSZ);
        s.x += v.x; s.y += v.y; s.z += v.z; s.w += v.w;
    }
    *(f4*)&x2[(size_t)(b * 2 + o) * HWSZ + p] = s;
}

// -----------------------------------------------------------------------------
// Kernel 3: per-b tail. Reads only the 4-MB LLC-hot x2 into a padded LDS
// image (serves row reads AND column reads conflict-free), then both conv
// branches concurrently, shifted combine, linear+sigmoid, outer product.
// 16 blocks x 1024 threads. LDS ~151 KB (fits 160 KB/CU).
// -----------------------------------------------------------------------------
__global__ __launch_bounds__(1024) void k3_rest(
    const float* __restrict__ x2g,
    const float* __restrict__ wwc,   // [2,128,5]
    const float* __restrict__ hwc,   // [2,5,128]
    const float* __restrict__ wlw, const float* __restrict__ wlb,
    const float* __restrict__ hlw, const float* __restrict__ hlb,
    float* __restrict__ out)
{
    __shared__ float x2l[2][SS][LP];      // x2 image, padded rows
    __shared__ float tw2[2][2][5][SS];    // [kpart][i][kw][wo] ww partials
    __shared__ float uh2[2][2][5][SS];    // [kpart][i][kh][ho] hw partials
    __shared__ float vbuf[2 * SS];
    __shared__ float rbuf[2 * SS];

    const int b   = blockIdx.x;
    const int tid = threadIdx.x;

    // ---- phase 0: global x2 -> padded LDS image (256 KB per block)
    {
        const float* xb = x2g + (size_t)b * 2 * HWSZ;
        #pragma unroll
        for (int it = 0; it < (2 * HWSZ / 4) / 1024; ++it) {   // 8 iters
            const int p = (it * 1024 + tid) * 4;
            const f4 v = *(const f4*)(xb + p);
            const int o   = p >> 14;
            const int pix = p & (HWSZ - 1);
            const int h   = pix >> 7;
            const int w   = pix & (SS - 1);
            x2l[o][h][w + 0] = v.x;
            x2l[o][h][w + 1] = v.y;
            x2l[o][h][w + 2] = v.z;
            x2l[o][h][w + 3] = v.w;
        }
    }
    __syncthreads();

    // ---- phase 1: both conv branches, 8 groups of 128 threads:
    // tid = [kp:1][br:1][i:1][lane:7] ; kp halves the 128-long reduction.
    {
        const int lane = tid & 127;
        const int i    = (tid >> 7) & 1;   // input channel (wave-uniform)
        const int br   = (tid >> 8) & 1;   // 0 = ww branch, 1 = hw branch
        const int kp   = tid >> 9;         // reduction half
        float acc[5] = {0.f, 0.f, 0.f, 0.f, 0.f};

        if (br == 0) {
            // tw2[kp][i][kw][wo] = sum_{kh half} x2l[i][kh][wo] * wwc[i,kh,kw]
            const float* wrow = wwc + i * (SS * 5);
            const int kh0 = kp * 64;
            #pragma unroll 8
            for (int kh = kh0; kh < kh0 + 64; ++kh) {
                const float xv = x2l[i][kh][lane];   // col read: LP=129, clean
                #pragma unroll
                for (int kw = 0; kw < 5; ++kw)
                    acc[kw] = fmaf(xv, wrow[kh * 5 + kw], acc[kw]);
            }
            #pragma unroll
            for (int kw = 0; kw < 5; ++kw) tw2[kp][i][kw][lane] = acc[kw];
        } else {
            // uh2[kp][i][kh][ho] = sum_{kw half} x2l[i][ho][kw] * hwc[i,kh,kw]
            const float* wrow = hwc + i * (5 * SS);
            const int kw0 = kp * 64;
            #pragma unroll 8
            for (int kw = kw0; kw < kw0 + 64; ++kw) {
                const float xv = x2l[i][lane][kw];   // row read
                #pragma unroll
                for (int kh = 0; kh < 5; ++kh)
                    acc[kh] = fmaf(xv, wrow[kh * SS + kw], acc[kh]);
            }
            #pragma unroll
            for (int kh = 0; kh < 5; ++kh) uh2[kp][i][kh][lane] = acc[kh];
        }
    }
    __syncthreads();

    // ---- phase 2: shifted 5-tap combine over {kp, i}
    if (tid < 256) {
        const int pos = tid & 127;
        float s = 0.f;
        if (tid < 128) {                       // ww branch, wo = pos
            #pragma unroll
            for (int kw = 0; kw < 5; ++kw) {
                const int wsrc = pos + kw - 2;
                if (wsrc >= 0 && wsrc < SS)
                    s += (tw2[0][0][kw][wsrc] + tw2[0][1][kw][wsrc])
                       + (tw2[1][0][kw][wsrc] + tw2[1][1][kw][wsrc]);
            }
        } else {                               // hw branch, ho = pos
            #pragma unroll
            for (int kh = 0; kh < 5; ++kh) {
                const int hsrc = pos + kh - 2;
                if (hsrc >= 0 && hsrc < SS)
                    s += (uh2[0][0][kh][hsrc] + uh2[0][1][kh][hsrc])
                       + (uh2[1][0][kh][hsrc] + uh2[1][1][kh][hsrc]);
            }
        }
        vbuf[tid] = s;
    }
    __syncthreads();

    // ---- phase 3: linear + sigmoid
    if (tid < 256) {
        const int j    = tid & 127;
        const int half = tid >> 7;             // 0 = ww, 1 = hw
        const float* lw  = (half == 0) ? wlw : hlw;
        const float* lb  = (half == 0) ? wlb : hlb;
        const float* vin = vbuf + half * SS;
        float s = lb[j];
        const f4* wr = (const f4*)(lw + (size_t)j * SS);
        #pragma unroll 4
        for (int k4 = 0; k4 < SS / 4; ++k4) {
            const f4 wv = wr[k4];
            s = fmaf(vin[4 * k4 + 0], wv.x, s);
            s = fmaf(vin[4 * k4 + 1], wv.y, s);
            s = fmaf(vin[4 * k4 + 2], wv.z, s);
            s = fmaf(vin[4 * k4 + 3], wv.w, s);
        }
        rbuf[tid] = 1.f / (1.f + expf(-s));
    }
    __syncthreads();

    // ---- phase 4: out[b,h,w] = hw2[h] * ww2[w]
    {
        float* ob = out + (size_t)b * HWSZ;
        #pragma unroll
        for (int it = 0; it < (HWSZ / 4) / 1024; ++it) {   // 4 iters
            const int p4 = it * 1024 + tid;
            const int h  = p4 >> 5;
            const int w0 = (p4 & 31) * 4;
            const float hv = rbuf[SS + h];
            f4 o;
            o.x = hv * rbuf[w0 + 0];
            o.y = hv * rbuf[w0 + 1];
            o.z = hv * rbuf[w0 + 2];
            o.w = hv * rbuf[w0 + 3];
            *(f4*)(ob + (size_t)h * SS + w0) = o;
        }
    }
}

extern "C" void kernel_launch(void* const* d_in, const int* in_sizes, int n_in,
                              void* d_out, int out_size, void* d_ws, size_t ws_size,
                              hipStream_t stream) {
    const float* x     = (const float*)d_in[0];  // [16,512,128,128]
    const float* wconv = (const float*)d_in[1];  // [2,512,1,1]
    const float* wwc   = (const float*)d_in[2];  // [1,2,128,5]
    const float* hwc   = (const float*)d_in[3];  // [1,2,5,128]
    const float* wlw   = (const float*)d_in[4];  // [128,128]
    const float* wlb   = (const float*)d_in[5];  // [128]
    const float* hlw   = (const float*)d_in[6];  // [128,128]
    const float* hlb   = (const float*)d_in[7];  // [128]
    float* out = (float*)d_out;                  // [16,128,128] fp32

    // workspace: part (32 MB) + x2 (4 MB)
    float* part = (float*)d_ws;
    float* x2   = part + (size_t)BB * NCH * 2 * HWSZ;

    k1a_partial<<<dim3(BB * NCH * 2), dim3(512), 0, stream>>>(x, wconv, part);
    k1b_reduce<<<dim3(BB * 2 * 16), dim3(256), 0, stream>>>(part, x2);
    k3_rest<<<dim3(BB), dim3(1024), 0, stream>>>(x2, wwc, hwc,
                                                 wlw, wlb, hlw, hlb, out);
}